// Round 1
// 819.230 us; speedup vs baseline: 1.0195x; 1.0195x over previous
//
#include <hip/hip_runtime.h>
#include <hip/hip_bf16.h>
#include <math.h>

#define NBAG 512
#define NPB 64
#define DIM 1024
#define NCLS 53
#define NSTEP 63
#define MAXROWS 16384  // level-1 worst case: 512 bags * 32 merges
#define LMAX 8         // levels 1..LMAX via batched GEMM; deeper via k_deep
                       // (measured: LMAX=4 -> k_deep 1391us; LMAX=14 -> +12 launches, +95us;
                       //  8-phase k_fc8 port for l<=2 -> +72us, reverted)

typedef __attribute__((ext_vector_type(8))) short short8;
typedef __attribute__((ext_vector_type(4))) short short4v;
typedef __attribute__((ext_vector_type(4))) float f32x4;

__device__ __forceinline__ short bf16bits(float x) {
  __hip_bfloat16 h = __float2bfloat16(x);
  return *reinterpret_cast<short*>(&h);
}

// fast tanh: 1 - 2/(e^{2x}+1). Feature path only — never in the node-weight
// computation (tree order must not change).
__device__ __forceinline__ float fast_tanh(float x) {
  float e = __expf(2.0f * x);
  return 1.0f - __fdividef(2.0f, e + 1.0f);
}

// global -> LDS direct copy, 16B per lane, dest = wave-uniform base + lane*16
__device__ __forceinline__ void gld16(const void* g, void* l) {
  __builtin_amdgcn_global_load_lds(
      (const __attribute__((address_space(1))) void*)g,
      (__attribute__((address_space(3))) void*)(unsigned)(uintptr_t)l,
      16, 0, 0);
}

// ---------------------------------------------------------------------------
// K1: per-bag node weights + bf16 tanh leaves + fused weight f32->bf16 tail.
// R12 rewrite: all three passes over the bag use 16B/lane vector loads.
// nw arithmetic is bitwise-identical to the proven R5 version:
//   - pass 1/3 stage each row via f32x4 -> per-wave LDS buffer, then the
//     reduction reads the exact original strided partition (l + 64j) in the
//     exact original order; butterfly shuffle order unchanged.
//   - pass 2 vectorizes ACROSS columns (per-column n-order 0..63 unchanged).
//   - tanh leaves are computed straight from the pass-1 registers (the old
//     second read of the row is gone).
// ---------------------------------------------------------------------------
__global__ __launch_bounds__(1024) void k_prep(const float* __restrict__ rep,
                                               float* __restrict__ nw,
                                               __hip_bfloat16* __restrict__ tfeats,
                                               const float* __restrict__ w1,
                                               __hip_bfloat16* __restrict__ w1b,
                                               const float* __restrict__ w2,
                                               __hip_bfloat16* __restrict__ w2b) {
  int b = blockIdx.x;
  const float* bag = rep + (size_t)b * NPB * DIM;
  __shared__ float inv_n[NPB];
  __shared__ float dist[NPB];
  __shared__ alignas(16) float S[DIM];
  __shared__ alignas(16) float rows[16][DIM];  // 64 KB: one row-buffer per wave
  int t = threadIdx.x, wave = t >> 6, lane = t & 63;

  // ---- pass 1: vec-load row -> {tanh+store from regs, LDS-staged exact norm}
  for (int n = wave; n < NPB; n += 16) {
    const f32x4* xr = (const f32x4*)(bag + (size_t)n * DIM);
    f32x4 v[4];
    #pragma unroll
    for (int k = 0; k < 4; k++) v[k] = xr[k * 64 + lane];

    f32x4* lr = (f32x4*)rows[wave];
    #pragma unroll
    for (int k = 0; k < 4; k++) lr[k * 64 + lane] = v[k];

    short4v* tr = (short4v*)(tfeats + ((((size_t)b << 6) + n) << 10));
    #pragma unroll
    for (int k = 0; k < 4; k++) {
      short4v o;
      o.x = bf16bits(fast_tanh(v[k].x)); o.y = bf16bits(fast_tanh(v[k].y));
      o.z = bf16bits(fast_tanh(v[k].z)); o.w = bf16bits(fast_tanh(v[k].w));
      tr[k * 64 + lane] = o;
    }

    // same-wave LDS write->read: drain lgkm, then read the exact original
    // strided partition in the exact original order.
    asm volatile("s_waitcnt lgkmcnt(0)" ::: "memory");
    float acc = 0.f;
    #pragma unroll
    for (int j = 0; j < 16; j++) {
      float f = rows[wave][j * 64 + lane];
      acc += f * f;
    }
    for (int off = 32; off; off >>= 1) acc += __shfl_xor(acc, off);
    if (lane == 0) inv_n[n] = 1.0f / sqrtf(acc);
  }
  __syncthreads();

  // ---- pass 2: S, vectorized across columns; per-column n-order unchanged
  if (t < 256) {
    const f32x4* br = (const f32x4*)bag;
    f32x4 acc = (f32x4){0.f, 0.f, 0.f, 0.f};
    #pragma unroll 16
    for (int n = 0; n < NPB; n++) {
      f32x4 v = br[n * 256 + t];
      float w = inv_n[n];
      acc.x += v.x * w; acc.y += v.y * w;
      acc.z += v.z * w; acc.w += v.w * w;
    }
    ((f32x4*)S)[t] = acc;
  }
  __syncthreads();

  // ---- pass 3: dist, LDS-staged exact-order dot with S
  for (int n = wave; n < NPB; n += 16) {
    const f32x4* xr = (const f32x4*)(bag + (size_t)n * DIM);
    f32x4* lr = (f32x4*)rows[wave];
    #pragma unroll
    for (int k = 0; k < 4; k++) lr[k * 64 + lane] = xr[k * 64 + lane];
    asm volatile("s_waitcnt lgkmcnt(0)" ::: "memory");
    float acc = 0.f;
    #pragma unroll
    for (int j = 0; j < 16; j++)
      acc += rows[wave][j * 64 + lane] * S[j * 64 + lane];
    for (int off = 32; off; off >>= 1) acc += __shfl_xor(acc, off);
    if (lane == 0) dist[n] = acc * inv_n[n];
  }
  __syncthreads();

  if (t < 64) {
    float v = dist[t], m = v;
    for (int off = 32; off; off >>= 1) m = fmaxf(m, __shfl_xor(m, off));
    float e = expf(v - m), s = e;
    for (int off = 32; off; off >>= 1) s += __shfl_xor(s, off);
    nw[b * NPB + t] = e / s;
  }

  // ---- fused weight conversion tail (vectorized, grid-strided)
  {
    const int nv1 = (DIM * 2 * DIM) / 4;
    const int nv2 = (DIM * DIM) / 4;
    for (int i = b * 1024 + t; i < nv1 + nv2; i += NBAG * 1024) {
      if (i < nv1) {
        f32x4 v = ((const f32x4*)w1)[i];
        short4v o;
        o.x = bf16bits(v.x); o.y = bf16bits(v.y);
        o.z = bf16bits(v.z); o.w = bf16bits(v.w);
        ((short4v*)w1b)[i] = o;
      } else {
        f32x4 v = ((const f32x4*)w2)[i - nv1];
        short4v o;
        o.x = bf16bits(v.x); o.y = bf16bits(v.y);
        o.z = bf16bits(v.z); o.w = bf16bits(v.w);
        ((short4v*)w2b)[i - nv1] = o;
      }
    }
  }
}

// ---------------------------------------------------------------------------
// K2: per-bag Huffman merge order + level. 4 bags per block.
// ---------------------------------------------------------------------------
__global__ __launch_bounds__(256) void k_merge_levels(const float* __restrict__ nw,
                                                      unsigned* __restrict__ lvlbuf,
                                                      unsigned* __restrict__ cnt) {
  int b = blockIdx.x * 4 + (threadIdx.x >> 6);
  int lane = threadIdx.x & 63;
  const float INF = __int_as_float(0x7f800000);
  float w = nw[b * NPB + lane];
  bool alive = true;
  int ready = 0;
  int mycnt = 0;

  for (int t = 0; t < NSTEP; t++) {
    float v = alive ? w : INF; int i = lane;
    for (int off = 32; off; off >>= 1) {
      float v2 = __shfl_xor(v, off); int j2 = __shfl_xor(i, off);
      if (v2 < v || (v2 == v && j2 < i)) { v = v2; i = j2; }
    }
    int i1 = i;
    float vv = (alive && lane != i1) ? w : INF; int ii = lane;
    for (int off = 32; off; off >>= 1) {
      float v2 = __shfl_xor(vv, off); int j2 = __shfl_xor(ii, off);
      if (v2 < vv || (v2 == vv && j2 < ii)) { vv = v2; ii = j2; }
    }
    int i2 = ii;
    float w1v = __shfl(w, i1), w2v = __shfl(w, i2);
    if (lane == i1) w = w1v + w2v;
    if (lane == i2) alive = false;
    int r1 = __shfl(ready, i1), r2 = __shfl(ready, i2);
    int lvl = max(r1, r2) + 1;
    int rank = __shfl(mycnt, lvl - 1);
    if (lane == lvl - 1) mycnt++;
    if (lane == i1) ready = lvl;
    if (lane == 0)
      lvlbuf[b * NSTEP + t] = (unsigned)i1 | ((unsigned)i2 << 6) |
                              ((unsigned)lvl << 12) | ((unsigned)rank << 18);
  }
  cnt[b * 64 + lane] = (unsigned)mycnt;
}

// K3: per-level exclusive scan over bags
__global__ __launch_bounds__(512) void k_bagscan(const unsigned* __restrict__ cnt,
                                                 unsigned* __restrict__ bagoff,
                                                 unsigned* __restrict__ levtot) {
  int l = blockIdx.x + 1;
  int b = threadIdx.x;
  __shared__ unsigned s[512];
  unsigned v = cnt[b * 64 + (l - 1)];
  s[b] = v; __syncthreads();
  for (int o = 1; o < 512; o <<= 1) {
    unsigned x = (b >= o) ? s[b - o] : 0u; __syncthreads();
    s[b] += x; __syncthreads();
  }
  bagoff[l * 512 + b] = s[b] - v;
  if (b == 511) levtot[l] = s[511];
}

// K5: scatter merges into level-sorted worklist (fused level-offset scan).
__global__ __launch_bounds__(256) void k_scatter(const unsigned* __restrict__ lvlbuf,
                                                 const unsigned* __restrict__ levtot,
                                                 const unsigned* __restrict__ bagoff,
                                                 unsigned* __restrict__ wl,
                                                 unsigned* __restrict__ off_out) {
  __shared__ unsigned off_s[65];
  int t = threadIdx.x;
  if (t < 64) {
    unsigned v = (t >= 1) ? levtot[t] : 0u;
    unsigned x = v;
    for (int o = 1; o < 64; o <<= 1) {
      unsigned y = __shfl_up(x, o);
      if (t >= o) x += y;
    }
    off_s[t] = x - v;
    if (t == 63) off_s[64] = x;
    if (blockIdx.x == 0) {
      off_out[t] = x - v;
      if (t == 63) off_out[64] = x;
    }
  }
  __syncthreads();

  int idx = blockIdx.x * 256 + t;
  int b = idx / NSTEP, st = idx % NSTEP;
  unsigned e = lvlbuf[idx];
  unsigned i1 = e & 63, i2 = (e >> 6) & 63, lvl = (e >> 12) & 63, rank = (e >> 18) & 31;
  unsigned pos = off_s[lvl] + bagoff[lvl * 512 + b] + rank;
  wl[pos] = (unsigned)b | (i1 << 9) | (i2 << 15) | ((st == NSTEP - 1 ? 1u : 0u) << 21);
}

// ---------------------------------------------------------------------------
// K7: batched MFMA GEMM for one level. BM=256 x BN=128, BK=64, 8 waves,
// wave-tile 64x64 (4M x 2N). Proven R11 body (bit-exact outputs).
// ---------------------------------------------------------------------------
template <int KTOT, bool FC1>
__global__ __launch_bounds__(512) void k_fc(const __hip_bfloat16* __restrict__ Asrc,
                                            const __hip_bfloat16* __restrict__ wB,
                                            const float* __restrict__ bias,
                                            const unsigned* __restrict__ wl,
                                            const unsigned* __restrict__ off,
                                            __hip_bfloat16* __restrict__ hbuf,
                                            __hip_bfloat16* __restrict__ tfeats,
                                            float* __restrict__ rootfeat,
                                            int level) {
  __shared__ alignas(16) short As[256 * 64];   // 32 KB
  __shared__ alignas(16) short Bs[128 * 64];   // 16 KB
  __shared__ unsigned wle[256];

  int nwg = (int)gridDim.x;
  int hw = (int)blockIdx.x;
  int q = nwg >> 3, r = nwg & 7;
  int xcd = hw & 7, ii = hw >> 3;
  int wid = (xcd < r ? xcd * (q + 1) : r * (q + 1) + (xcd - r) * q) + ii;
  int nbase = (wid & 7) * 128;     // 8 N-panels of 128
  int mbase = (wid >> 3) * 256;    // M-tiles of 256

  int c0 = (int)off[level];
  int count = (int)off[level + 1] - c0;
  if (mbase >= count) return;
  int t = threadIdx.x, wv = t >> 6, lane = t & 63;
  if (t < 256) wle[t] = wl[c0 + min(mbase + t, count - 1)];
  __syncthreads();

  int lr = lane >> 3, p = lane & 7;
  const __hip_bfloat16* aptrA[4];
  const __hip_bfloat16* aptrB[4];
  const __hip_bfloat16* bptr[2];
  #pragma unroll
  for (int c = 0; c < 4; c++) {
    int rc = (wv * 4 + c) * 8 + lr;    // 0..255: A-row this lane stages
    int u = p ^ (rc & 7);
    if (FC1) {
      unsigned e = wle[rc];
      int bidx = e & 511, s1 = (e >> 9) & 63, s2 = (e >> 15) & 63;
      aptrA[c] = Asrc + (((size_t)(bidx << 6) + s1) << 10) + (u << 3);
      aptrB[c] = Asrc + (((size_t)(bidx << 6) + s2) << 10) + (u << 3);
    } else {
      aptrA[c] = Asrc + ((size_t)(mbase + rc) << 10) + (u << 3);
      aptrB[c] = aptrA[c];
    }
  }
  #pragma unroll
  for (int c = 0; c < 2; c++) {
    int rc = (wv * 2 + c) * 8 + lr;    // 0..127: B-row this lane stages
    int u = p ^ (rc & 7);
    bptr[c] = wB + (size_t)(nbase + rc) * KTOT + (u << 3);
  }

  f32x4 acc[4][4];
  #pragma unroll
  for (int i = 0; i < 4; i++)
    #pragma unroll
    for (int j = 0; j < 4; j++) acc[i][j] = (f32x4){0.f, 0.f, 0.f, 0.f};

  int mh = wv >> 1, nh = wv & 1;       // 4M x 2N wave grid

  for (int k0 = 0; k0 < KTOT; k0 += 64) {
    #pragma unroll
    for (int c = 0; c < 4; c++) {
      int ch = wv * 4 + c;             // 0..31 A-chunks (8 rows each)
      const __hip_bfloat16* g =
          (FC1 && k0 >= DIM) ? (aptrB[c] + (k0 - DIM)) : (aptrA[c] + k0);
      gld16(g, &As[ch << 9]);
    }
    #pragma unroll
    for (int c = 0; c < 2; c++) {
      int ch = wv * 2 + c;             // 0..15 B-chunks
      gld16(bptr[c] + k0, &Bs[ch << 9]);
    }
    __syncthreads();
    #pragma unroll
    for (int kc = 0; kc < 2; kc++) {
      short8 a[4], bb[4];
      #pragma unroll
      for (int mi = 0; mi < 4; mi++) {
        int rr = mh * 64 + mi * 16 + (lane & 15);
        int u = (kc * 4 + (lane >> 4)) ^ (rr & 7);
        a[mi] = *(const short8*)&As[rr * 64 + u * 8];
      }
      #pragma unroll
      for (int ni = 0; ni < 4; ni++) {
        int rr = nh * 64 + ni * 16 + (lane & 15);
        int u = (kc * 4 + (lane >> 4)) ^ (rr & 7);
        bb[ni] = *(const short8*)&Bs[rr * 64 + u * 8];
      }
      #pragma unroll
      for (int mi = 0; mi < 4; mi++)
        #pragma unroll
        for (int ni = 0; ni < 4; ni++)
          acc[mi][ni] = __builtin_amdgcn_mfma_f32_16x16x32_bf16(a[mi], bb[ni],
                                                                acc[mi][ni], 0, 0, 0);
    }
    __syncthreads();
  }

  #pragma unroll
  for (int mi = 0; mi < 4; mi++) {
    #pragma unroll
    for (int reg = 0; reg < 4; reg++) {
      int m_loc = mh * 64 + mi * 16 + ((lane >> 4) << 2) + reg;
      int m = mbase + m_loc;
      if (m >= count) continue;
      #pragma unroll
      for (int ni = 0; ni < 4; ni++) {
        int n = nbase + nh * 64 + ni * 16 + (lane & 15);
        float v = acc[mi][ni][reg] + bias[n];
        if (FC1) {
          hbuf[(size_t)m * DIM + n] = __float2bfloat16(fast_tanh(v));
        } else {
          unsigned e = wle[m_loc];
          int bidx = e & 511, d = (e >> 9) & 63;
          tfeats[(((size_t)(bidx << 6) + d) << 10) + n] = __float2bfloat16(fast_tanh(v));
          if (e >> 21) rootfeat[(size_t)bidx * DIM + n] = v;
        }
      }
    }
  }
}

// ---------------------------------------------------------------------------
// K7b: deep-level fallback (> LMAX) + fused final scores. One block per bag.
// ---------------------------------------------------------------------------
#define XP(i) ((i) + ((i) >> 3))
__global__ __launch_bounds__(1024) void k_deep(__hip_bfloat16* __restrict__ tfeats,
                                               const __hip_bfloat16* __restrict__ w1b,
                                               const float* __restrict__ b1,
                                               const __hip_bfloat16* __restrict__ w2b,
                                               const float* __restrict__ b2,
                                               const unsigned* __restrict__ lvlbuf,
                                               float* __restrict__ rootfeat,
                                               const float* __restrict__ rel,
                                               float* __restrict__ out) {
  int b = blockIdx.x;
  __shared__ float xs[XP(2048) + 1];
  __shared__ float hs[XP(1024) + 1];
  __shared__ unsigned steps[NSTEP];
  int t = threadIdx.x, wv = t >> 6, lane = t & 63;
  if (t < NSTEP) steps[t] = lvlbuf[b * NSTEP + t];
  __syncthreads();

  for (int s = 0; s < NSTEP; s++) {
    unsigned e = steps[s];
    int lvl = (int)((e >> 12) & 63);
    if (lvl <= LMAX) continue;
    int i1 = (int)(e & 63), i2 = (int)((e >> 6) & 63);
    const __hip_bfloat16* r1 = tfeats + ((((size_t)b << 6) + i1) << 10);
    const __hip_bfloat16* r2 = tfeats + ((((size_t)b << 6) + i2) << 10);
    xs[XP(t)] = __bfloat162float(r1[t]);
    xs[XP(1024 + t)] = __bfloat162float(r2[t]);
    __syncthreads();
    for (int r = 0; r < 64; r++) {
      int n = r * 16 + wv;
      const short8* wr = (const short8*)(w1b + (size_t)n * 2048);
      float acc = 0.f;
      for (int c = lane; c < 256; c += 64) {
        short8 w8 = wr[c];
        #pragma unroll
        for (int j = 0; j < 8; j++) {
          float wf = __uint_as_float(((unsigned)(unsigned short)w8[j]) << 16);
          acc += xs[XP(c * 8 + j)] * wf;
        }
      }
      for (int off = 32; off; off >>= 1) acc += __shfl_xor(acc, off);
      if (lane == 0) hs[XP(n)] = fast_tanh(acc + b1[n]);
    }
    __syncthreads();
    for (int r = 0; r < 64; r++) {
      int n = r * 16 + wv;
      const short8* wr = (const short8*)(w2b + (size_t)n * 1024);
      float acc = 0.f;
      for (int c = lane; c < 128; c += 64) {
        short8 w8 = wr[c];
        #pragma unroll
        for (int j = 0; j < 8; j++) {
          float wf = __uint_as_float(((unsigned)(unsigned short)w8[j]) << 16);
          acc += hs[XP(c * 8 + j)] * wf;
        }
      }
      for (int off = 32; off; off >>= 1) acc += __shfl_xor(acc, off);
      if (lane == 0) {
        float f = acc + b2[n];
        tfeats[((((size_t)b << 6) + i1) << 10) + n] = __float2bfloat16(fast_tanh(f));
        if (s == NSTEP - 1) rootfeat[(size_t)b * DIM + n] = f;
      }
    }
    __syncthreads();
  }

  // ---- fused scores: sigmoid(rootfeat[b] @ rel^T)
  __shared__ float fr[DIM];
  fr[t] = rootfeat[(size_t)b * DIM + t];
  __syncthreads();
  for (int c = wv; c < NCLS; c += 16) {
    const float* w = rel + (size_t)c * DIM;
    float acc = 0.f;
    for (int j = lane; j < DIM; j += 64) acc += fr[j] * w[j];
    for (int off = 32; off; off >>= 1) acc += __shfl_xor(acc, off);
    if (lane == 0) out[b * NCLS + c] = 1.0f / (1.0f + expf(-acc));
  }
}

// ---------------------------------------------------------------------------
extern "C" void kernel_launch(void* const* d_in, const int* in_sizes, int n_in,
                              void* d_out, int out_size, void* d_ws, size_t ws_size,
                              hipStream_t stream) {
  const float* rep = (const float*)d_in[0];
  const float* w1  = (const float*)d_in[1];
  const float* b1  = (const float*)d_in[2];
  const float* w2  = (const float*)d_in[3];
  const float* b2  = (const float*)d_in[4];
  const float* rel = (const float*)d_in[5];
  float* out = (float*)d_out;

  char* ws = (char*)d_ws;
  __hip_bfloat16* tfeats = (__hip_bfloat16*)ws; ws += (size_t)NBAG * NPB * DIM * 2;
  __hip_bfloat16* hbuf   = (__hip_bfloat16*)ws; ws += (size_t)MAXROWS * DIM * 2;
  __hip_bfloat16* w1b    = (__hip_bfloat16*)ws; ws += (size_t)DIM * 2 * DIM * 2;
  __hip_bfloat16* w2b    = (__hip_bfloat16*)ws; ws += (size_t)DIM * DIM * 2;
  float* rootfeat        = (float*)ws;          ws += (size_t)NBAG * DIM * 4;
  float* nw              = (float*)ws;          ws += (size_t)NBAG * NPB * 4;
  unsigned* lvlbuf       = (unsigned*)ws;       ws += (size_t)NBAG * NSTEP * 4;
  unsigned* cnt          = (unsigned*)ws;       ws += (size_t)NBAG * 64 * 4;
  unsigned* bagoff       = (unsigned*)ws;       ws += (size_t)64 * 512 * 4;
  unsigned* levtot       = (unsigned*)ws;       ws += 64 * 4;
  unsigned* off          = (unsigned*)ws;       ws += 128 * 4;
  unsigned* wl           = (unsigned*)ws;       ws += (size_t)NBAG * NSTEP * 4;

  k_prep<<<NBAG, 1024, 0, stream>>>(rep, nw, tfeats, w1, w1b, w2, w2b);
  k_merge_levels<<<NBAG / 4, 256, 0, stream>>>(nw, lvlbuf, cnt);
  k_bagscan<<<63, 512, 0, stream>>>(cnt, bagoff, levtot);
  k_scatter<<<126, 256, 0, stream>>>(lvlbuf, levtot, bagoff, wl, off);

  for (int l = 1; l <= LMAX; l++) {
    int cap = 64 / (l + 1); if (cap > 32) cap = 32;
    int capM = 2 * cap;                       // 256-row M-tiles capacity
    k_fc<2 * DIM, true><<<dim3(8 * capM), 512, 0, stream>>>(
        tfeats, w1b, b1, wl, off, hbuf, nullptr, nullptr, l);
    k_fc<DIM, false><<<dim3(8 * capM), 512, 0, stream>>>(
        hbuf, w2b, b2, wl, off, nullptr, tfeats, rootfeat, l);
  }
  k_deep<<<NBAG, 1024, 0, stream>>>(tfeats, w1b, b1, w2b, b2, lvlbuf, rootfeat,
                                    rel, out);
}

// Round 2
// 817.963 us; speedup vs baseline: 1.0211x; 1.0015x over previous
//
#include <hip/hip_runtime.h>
#include <hip/hip_bf16.h>
#include <math.h>

#define NBAG 512
#define NPB 64
#define DIM 1024
#define NCLS 53
#define NSTEP 63
#define MAXROWS 16384  // level-1 worst case: 512 bags * 32 merges
#define LMAX 8         // levels 1..LMAX via batched GEMM; deeper via k_deep
                       // (measured: LMAX=4 -> k_deep 1391us; LMAX=14 -> +12 launches, +95us;
                       //  8-phase k_fc8 port for l<=2 -> +72us, reverted)

typedef __attribute__((ext_vector_type(8))) short short8;
typedef __attribute__((ext_vector_type(4))) short short4v;
typedef __attribute__((ext_vector_type(4))) float f32x4;

__device__ __forceinline__ short bf16bits(float x) {
  __hip_bfloat16 h = __float2bfloat16(x);
  return *reinterpret_cast<short*>(&h);
}

// fast tanh: 1 - 2/(e^{2x}+1). Feature path only — never in the node-weight
// computation (tree order must not change).
__device__ __forceinline__ float fast_tanh(float x) {
  float e = __expf(2.0f * x);
  return 1.0f - __fdividef(2.0f, e + 1.0f);
}

// global -> LDS direct copy, 16B per lane, dest = wave-uniform base + lane*16
__device__ __forceinline__ void gld16(const void* g, void* l) {
  __builtin_amdgcn_global_load_lds(
      (const __attribute__((address_space(1))) void*)g,
      (__attribute__((address_space(3))) void*)(unsigned)(uintptr_t)l,
      16, 0, 0);
}

// ---------------------------------------------------------------------------
// K1: per-bag node weights + bf16 tanh leaves + fused weight f32->bf16 tail.
// R13: half-row LDS staging (32 KB instead of 64 KB) so block LDS stays
// well under 64 KB -> 2 blocks/CU resident (R12's 70 KB halved occupancy
// to 43%). nw arithmetic remains bitwise-identical: half 0 carries the
// j=0..7 terms of the original strided reduction, half 1 carries j=8..15,
// processed in that order; butterfly shuffle order unchanged.
// ---------------------------------------------------------------------------
__global__ __launch_bounds__(1024) void k_prep(const float* __restrict__ rep,
                                               float* __restrict__ nw,
                                               __hip_bfloat16* __restrict__ tfeats,
                                               const float* __restrict__ w1,
                                               __hip_bfloat16* __restrict__ w1b,
                                               const float* __restrict__ w2,
                                               __hip_bfloat16* __restrict__ w2b) {
  int b = blockIdx.x;
  const float* bag = rep + (size_t)b * NPB * DIM;
  __shared__ float inv_n[NPB];
  __shared__ float dist[NPB];
  __shared__ alignas(16) float S[DIM];
  __shared__ alignas(16) float rows[16][512];  // 32 KB: half-row per wave
  int t = threadIdx.x, wave = t >> 6, lane = t & 63;

  // ---- pass 1: vec-load row -> {tanh+store from regs, LDS-staged exact norm}
  for (int n = wave; n < NPB; n += 16) {
    const f32x4* xr = (const f32x4*)(bag + (size_t)n * DIM);
    f32x4 v[4];
    #pragma unroll
    for (int k = 0; k < 4; k++) v[k] = xr[k * 64 + lane];

    short4v* tr = (short4v*)(tfeats + ((((size_t)b << 6) + n) << 10));
    #pragma unroll
    for (int k = 0; k < 4; k++) {
      short4v o;
      o.x = bf16bits(fast_tanh(v[k].x)); o.y = bf16bits(fast_tanh(v[k].y));
      o.z = bf16bits(fast_tanh(v[k].z)); o.w = bf16bits(fast_tanh(v[k].w));
      tr[k * 64 + lane] = o;
    }

    // half-row staging: exact original order (j ascending across halves).
    f32x4* lr = (f32x4*)rows[wave];
    float acc = 0.f;
    #pragma unroll
    for (int h = 0; h < 2; h++) {
      lr[lane] = v[2 * h];
      lr[64 + lane] = v[2 * h + 1];
      // same-wave DS ops are processed in issue order; drain so the reads'
      // data is register-available, and fence the compiler between halves.
      asm volatile("s_waitcnt lgkmcnt(0)" ::: "memory");
      #pragma unroll
      for (int j = 0; j < 8; j++) {
        float f = rows[wave][j * 64 + lane];
        acc += f * f;
      }
      asm volatile("" ::: "memory");  // keep h=1 writes after h=0 reads
    }
    for (int off = 32; off; off >>= 1) acc += __shfl_xor(acc, off);
    if (lane == 0) inv_n[n] = 1.0f / sqrtf(acc);
  }
  __syncthreads();

  // ---- pass 2: S, vectorized across columns; per-column n-order unchanged
  if (t < 256) {
    const f32x4* br = (const f32x4*)bag;
    f32x4 acc = (f32x4){0.f, 0.f, 0.f, 0.f};
    #pragma unroll 16
    for (int n = 0; n < NPB; n++) {
      f32x4 v = br[n * 256 + t];
      float w = inv_n[n];
      acc.x += v.x * w; acc.y += v.y * w;
      acc.z += v.z * w; acc.w += v.w * w;
    }
    ((f32x4*)S)[t] = acc;
  }
  __syncthreads();

  // ---- pass 3: dist, half-row LDS-staged exact-order dot with S
  for (int n = wave; n < NPB; n += 16) {
    const f32x4* xr = (const f32x4*)(bag + (size_t)n * DIM);
    f32x4 v[4];
    #pragma unroll
    for (int k = 0; k < 4; k++) v[k] = xr[k * 64 + lane];
    f32x4* lr = (f32x4*)rows[wave];
    float acc = 0.f;
    #pragma unroll
    for (int h = 0; h < 2; h++) {
      lr[lane] = v[2 * h];
      lr[64 + lane] = v[2 * h + 1];
      asm volatile("s_waitcnt lgkmcnt(0)" ::: "memory");
      #pragma unroll
      for (int j = 0; j < 8; j++)
        acc += rows[wave][j * 64 + lane] * S[(h * 8 + j) * 64 + lane];
      asm volatile("" ::: "memory");
    }
    for (int off = 32; off; off >>= 1) acc += __shfl_xor(acc, off);
    if (lane == 0) dist[n] = acc * inv_n[n];
  }
  __syncthreads();

  if (t < 64) {
    float v = dist[t], m = v;
    for (int off = 32; off; off >>= 1) m = fmaxf(m, __shfl_xor(m, off));
    float e = expf(v - m), s = e;
    for (int off = 32; off; off >>= 1) s += __shfl_xor(s, off);
    nw[b * NPB + t] = e / s;
  }

  // ---- fused weight conversion tail (vectorized, grid-strided)
  {
    const int nv1 = (DIM * 2 * DIM) / 4;
    const int nv2 = (DIM * DIM) / 4;
    for (int i = b * 1024 + t; i < nv1 + nv2; i += NBAG * 1024) {
      if (i < nv1) {
        f32x4 v = ((const f32x4*)w1)[i];
        short4v o;
        o.x = bf16bits(v.x); o.y = bf16bits(v.y);
        o.z = bf16bits(v.z); o.w = bf16bits(v.w);
        ((short4v*)w1b)[i] = o;
      } else {
        f32x4 v = ((const f32x4*)w2)[i - nv1];
        short4v o;
        o.x = bf16bits(v.x); o.y = bf16bits(v.y);
        o.z = bf16bits(v.z); o.w = bf16bits(v.w);
        ((short4v*)w2b)[i - nv1] = o;
      }
    }
  }
}

// ---------------------------------------------------------------------------
// K2: per-bag Huffman merge order + level. 4 bags per block.
// ---------------------------------------------------------------------------
__global__ __launch_bounds__(256) void k_merge_levels(const float* __restrict__ nw,
                                                      unsigned* __restrict__ lvlbuf,
                                                      unsigned* __restrict__ cnt) {
  int b = blockIdx.x * 4 + (threadIdx.x >> 6);
  int lane = threadIdx.x & 63;
  const float INF = __int_as_float(0x7f800000);
  float w = nw[b * NPB + lane];
  bool alive = true;
  int ready = 0;
  int mycnt = 0;

  for (int t = 0; t < NSTEP; t++) {
    float v = alive ? w : INF; int i = lane;
    for (int off = 32; off; off >>= 1) {
      float v2 = __shfl_xor(v, off); int j2 = __shfl_xor(i, off);
      if (v2 < v || (v2 == v && j2 < i)) { v = v2; i = j2; }
    }
    int i1 = i;
    float vv = (alive && lane != i1) ? w : INF; int ii = lane;
    for (int off = 32; off; off >>= 1) {
      float v2 = __shfl_xor(vv, off); int j2 = __shfl_xor(ii, off);
      if (v2 < vv || (v2 == vv && j2 < ii)) { vv = v2; ii = j2; }
    }
    int i2 = ii;
    float w1v = __shfl(w, i1), w2v = __shfl(w, i2);
    if (lane == i1) w = w1v + w2v;
    if (lane == i2) alive = false;
    int r1 = __shfl(ready, i1), r2 = __shfl(ready, i2);
    int lvl = max(r1, r2) + 1;
    int rank = __shfl(mycnt, lvl - 1);
    if (lane == lvl - 1) mycnt++;
    if (lane == i1) ready = lvl;
    if (lane == 0)
      lvlbuf[b * NSTEP + t] = (unsigned)i1 | ((unsigned)i2 << 6) |
                              ((unsigned)lvl << 12) | ((unsigned)rank << 18);
  }
  cnt[b * 64 + lane] = (unsigned)mycnt;
}

// K3: per-level exclusive scan over bags
__global__ __launch_bounds__(512) void k_bagscan(const unsigned* __restrict__ cnt,
                                                 unsigned* __restrict__ bagoff,
                                                 unsigned* __restrict__ levtot) {
  int l = blockIdx.x + 1;
  int b = threadIdx.x;
  __shared__ unsigned s[512];
  unsigned v = cnt[b * 64 + (l - 1)];
  s[b] = v; __syncthreads();
  for (int o = 1; o < 512; o <<= 1) {
    unsigned x = (b >= o) ? s[b - o] : 0u; __syncthreads();
    s[b] += x; __syncthreads();
  }
  bagoff[l * 512 + b] = s[b] - v;
  if (b == 511) levtot[l] = s[511];
}

// K5: scatter merges into level-sorted worklist (fused level-offset scan).
__global__ __launch_bounds__(256) void k_scatter(const unsigned* __restrict__ lvlbuf,
                                                 const unsigned* __restrict__ levtot,
                                                 const unsigned* __restrict__ bagoff,
                                                 unsigned* __restrict__ wl,
                                                 unsigned* __restrict__ off_out) {
  __shared__ unsigned off_s[65];
  int t = threadIdx.x;
  if (t < 64) {
    unsigned v = (t >= 1) ? levtot[t] : 0u;
    unsigned x = v;
    for (int o = 1; o < 64; o <<= 1) {
      unsigned y = __shfl_up(x, o);
      if (t >= o) x += y;
    }
    off_s[t] = x - v;
    if (t == 63) off_s[64] = x;
    if (blockIdx.x == 0) {
      off_out[t] = x - v;
      if (t == 63) off_out[64] = x;
    }
  }
  __syncthreads();

  int idx = blockIdx.x * 256 + t;
  int b = idx / NSTEP, st = idx % NSTEP;
  unsigned e = lvlbuf[idx];
  unsigned i1 = e & 63, i2 = (e >> 6) & 63, lvl = (e >> 12) & 63, rank = (e >> 18) & 31;
  unsigned pos = off_s[lvl] + bagoff[lvl * 512 + b] + rank;
  wl[pos] = (unsigned)b | (i1 << 9) | (i2 << 15) | ((st == NSTEP - 1 ? 1u : 0u) << 21);
}

// ---------------------------------------------------------------------------
// K7: batched MFMA GEMM for one level. BM=256 x BN=128, BK=64, 8 waves,
// wave-tile 64x64 (4M x 2N). Proven R11 body (bit-exact outputs).
// ---------------------------------------------------------------------------
template <int KTOT, bool FC1>
__global__ __launch_bounds__(512) void k_fc(const __hip_bfloat16* __restrict__ Asrc,
                                            const __hip_bfloat16* __restrict__ wB,
                                            const float* __restrict__ bias,
                                            const unsigned* __restrict__ wl,
                                            const unsigned* __restrict__ off,
                                            __hip_bfloat16* __restrict__ hbuf,
                                            __hip_bfloat16* __restrict__ tfeats,
                                            float* __restrict__ rootfeat,
                                            int level) {
  __shared__ alignas(16) short As[256 * 64];   // 32 KB
  __shared__ alignas(16) short Bs[128 * 64];   // 16 KB
  __shared__ unsigned wle[256];

  int nwg = (int)gridDim.x;
  int hw = (int)blockIdx.x;
  int q = nwg >> 3, r = nwg & 7;
  int xcd = hw & 7, ii = hw >> 3;
  int wid = (xcd < r ? xcd * (q + 1) : r * (q + 1) + (xcd - r) * q) + ii;
  int nbase = (wid & 7) * 128;     // 8 N-panels of 128
  int mbase = (wid >> 3) * 256;    // M-tiles of 256

  int c0 = (int)off[level];
  int count = (int)off[level + 1] - c0;
  if (mbase >= count) return;
  int t = threadIdx.x, wv = t >> 6, lane = t & 63;
  if (t < 256) wle[t] = wl[c0 + min(mbase + t, count - 1)];
  __syncthreads();

  int lr = lane >> 3, p = lane & 7;
  const __hip_bfloat16* aptrA[4];
  const __hip_bfloat16* aptrB[4];
  const __hip_bfloat16* bptr[2];
  #pragma unroll
  for (int c = 0; c < 4; c++) {
    int rc = (wv * 4 + c) * 8 + lr;    // 0..255: A-row this lane stages
    int u = p ^ (rc & 7);
    if (FC1) {
      unsigned e = wle[rc];
      int bidx = e & 511, s1 = (e >> 9) & 63, s2 = (e >> 15) & 63;
      aptrA[c] = Asrc + (((size_t)(bidx << 6) + s1) << 10) + (u << 3);
      aptrB[c] = Asrc + (((size_t)(bidx << 6) + s2) << 10) + (u << 3);
    } else {
      aptrA[c] = Asrc + ((size_t)(mbase + rc) << 10) + (u << 3);
      aptrB[c] = aptrA[c];
    }
  }
  #pragma unroll
  for (int c = 0; c < 2; c++) {
    int rc = (wv * 2 + c) * 8 + lr;    // 0..127: B-row this lane stages
    int u = p ^ (rc & 7);
    bptr[c] = wB + (size_t)(nbase + rc) * KTOT + (u << 3);
  }

  f32x4 acc[4][4];
  #pragma unroll
  for (int i = 0; i < 4; i++)
    #pragma unroll
    for (int j = 0; j < 4; j++) acc[i][j] = (f32x4){0.f, 0.f, 0.f, 0.f};

  int mh = wv >> 1, nh = wv & 1;       // 4M x 2N wave grid

  for (int k0 = 0; k0 < KTOT; k0 += 64) {
    #pragma unroll
    for (int c = 0; c < 4; c++) {
      int ch = wv * 4 + c;             // 0..31 A-chunks (8 rows each)
      const __hip_bfloat16* g =
          (FC1 && k0 >= DIM) ? (aptrB[c] + (k0 - DIM)) : (aptrA[c] + k0);
      gld16(g, &As[ch << 9]);
    }
    #pragma unroll
    for (int c = 0; c < 2; c++) {
      int ch = wv * 2 + c;             // 0..15 B-chunks
      gld16(bptr[c] + k0, &Bs[ch << 9]);
    }
    __syncthreads();
    #pragma unroll
    for (int kc = 0; kc < 2; kc++) {
      short8 a[4], bb[4];
      #pragma unroll
      for (int mi = 0; mi < 4; mi++) {
        int rr = mh * 64 + mi * 16 + (lane & 15);
        int u = (kc * 4 + (lane >> 4)) ^ (rr & 7);
        a[mi] = *(const short8*)&As[rr * 64 + u * 8];
      }
      #pragma unroll
      for (int ni = 0; ni < 4; ni++) {
        int rr = nh * 64 + ni * 16 + (lane & 15);
        int u = (kc * 4 + (lane >> 4)) ^ (rr & 7);
        bb[ni] = *(const short8*)&Bs[rr * 64 + u * 8];
      }
      #pragma unroll
      for (int mi = 0; mi < 4; mi++)
        #pragma unroll
        for (int ni = 0; ni < 4; ni++)
          acc[mi][ni] = __builtin_amdgcn_mfma_f32_16x16x32_bf16(a[mi], bb[ni],
                                                                acc[mi][ni], 0, 0, 0);
    }
    __syncthreads();
  }

  #pragma unroll
  for (int mi = 0; mi < 4; mi++) {
    #pragma unroll
    for (int reg = 0; reg < 4; reg++) {
      int m_loc = mh * 64 + mi * 16 + ((lane >> 4) << 2) + reg;
      int m = mbase + m_loc;
      if (m >= count) continue;
      #pragma unroll
      for (int ni = 0; ni < 4; ni++) {
        int n = nbase + nh * 64 + ni * 16 + (lane & 15);
        float v = acc[mi][ni][reg] + bias[n];
        if (FC1) {
          hbuf[(size_t)m * DIM + n] = __float2bfloat16(fast_tanh(v));
        } else {
          unsigned e = wle[m_loc];
          int bidx = e & 511, d = (e >> 9) & 63;
          tfeats[(((size_t)(bidx << 6) + d) << 10) + n] = __float2bfloat16(fast_tanh(v));
          if (e >> 21) rootfeat[(size_t)bidx * DIM + n] = v;
        }
      }
    }
  }
}

// ---------------------------------------------------------------------------
// K7b: deep-level fallback (> LMAX) + fused final scores. One block per bag.
// ---------------------------------------------------------------------------
#define XP(i) ((i) + ((i) >> 3))
__global__ __launch_bounds__(1024) void k_deep(__hip_bfloat16* __restrict__ tfeats,
                                               const __hip_bfloat16* __restrict__ w1b,
                                               const float* __restrict__ b1,
                                               const __hip_bfloat16* __restrict__ w2b,
                                               const float* __restrict__ b2,
                                               const unsigned* __restrict__ lvlbuf,
                                               float* __restrict__ rootfeat,
                                               const float* __restrict__ rel,
                                               float* __restrict__ out) {
  int b = blockIdx.x;
  __shared__ float xs[XP(2048) + 1];
  __shared__ float hs[XP(1024) + 1];
  __shared__ unsigned steps[NSTEP];
  int t = threadIdx.x, wv = t >> 6, lane = t & 63;
  if (t < NSTEP) steps[t] = lvlbuf[b * NSTEP + t];
  __syncthreads();

  for (int s = 0; s < NSTEP; s++) {
    unsigned e = steps[s];
    int lvl = (int)((e >> 12) & 63);
    if (lvl <= LMAX) continue;
    int i1 = (int)(e & 63), i2 = (int)((e >> 6) & 63);
    const __hip_bfloat16* r1 = tfeats + ((((size_t)b << 6) + i1) << 10);
    const __hip_bfloat16* r2 = tfeats + ((((size_t)b << 6) + i2) << 10);
    xs[XP(t)] = __bfloat162float(r1[t]);
    xs[XP(1024 + t)] = __bfloat162float(r2[t]);
    __syncthreads();
    for (int r = 0; r < 64; r++) {
      int n = r * 16 + wv;
      const short8* wr = (const short8*)(w1b + (size_t)n * 2048);
      float acc = 0.f;
      for (int c = lane; c < 256; c += 64) {
        short8 w8 = wr[c];
        #pragma unroll
        for (int j = 0; j < 8; j++) {
          float wf = __uint_as_float(((unsigned)(unsigned short)w8[j]) << 16);
          acc += xs[XP(c * 8 + j)] * wf;
        }
      }
      for (int off = 32; off; off >>= 1) acc += __shfl_xor(acc, off);
      if (lane == 0) hs[XP(n)] = fast_tanh(acc + b1[n]);
    }
    __syncthreads();
    for (int r = 0; r < 64; r++) {
      int n = r * 16 + wv;
      const short8* wr = (const short8*)(w2b + (size_t)n * 1024);
      float acc = 0.f;
      for (int c = lane; c < 128; c += 64) {
        short8 w8 = wr[c];
        #pragma unroll
        for (int j = 0; j < 8; j++) {
          float wf = __uint_as_float(((unsigned)(unsigned short)w8[j]) << 16);
          acc += hs[XP(c * 8 + j)] * wf;
        }
      }
      for (int off = 32; off; off >>= 1) acc += __shfl_xor(acc, off);
      if (lane == 0) {
        float f = acc + b2[n];
        tfeats[((((size_t)b << 6) + i1) << 10) + n] = __float2bfloat16(fast_tanh(f));
        if (s == NSTEP - 1) rootfeat[(size_t)b * DIM + n] = f;
      }
    }
    __syncthreads();
  }

  // ---- fused scores: sigmoid(rootfeat[b] @ rel^T)
  __shared__ float fr[DIM];
  fr[t] = rootfeat[(size_t)b * DIM + t];
  __syncthreads();
  for (int c = wv; c < NCLS; c += 16) {
    const float* w = rel + (size_t)c * DIM;
    float acc = 0.f;
    for (int j = lane; j < DIM; j += 64) acc += fr[j] * w[j];
    for (int off = 32; off; off >>= 1) acc += __shfl_xor(acc, off);
    if (lane == 0) out[b * NCLS + c] = 1.0f / (1.0f + expf(-acc));
  }
}

// ---------------------------------------------------------------------------
extern "C" void kernel_launch(void* const* d_in, const int* in_sizes, int n_in,
                              void* d_out, int out_size, void* d_ws, size_t ws_size,
                              hipStream_t stream) {
  const float* rep = (const float*)d_in[0];
  const float* w1  = (const float*)d_in[1];
  const float* b1  = (const float*)d_in[2];
  const float* w2  = (const float*)d_in[3];
  const float* b2  = (const float*)d_in[4];
  const float* rel = (const float*)d_in[5];
  float* out = (float*)d_out;

  char* ws = (char*)d_ws;
  __hip_bfloat16* tfeats = (__hip_bfloat16*)ws; ws += (size_t)NBAG * NPB * DIM * 2;
  __hip_bfloat16* hbuf   = (__hip_bfloat16*)ws; ws += (size_t)MAXROWS * DIM * 2;
  __hip_bfloat16* w1b    = (__hip_bfloat16*)ws; ws += (size_t)DIM * 2 * DIM * 2;
  __hip_bfloat16* w2b    = (__hip_bfloat16*)ws; ws += (size_t)DIM * DIM * 2;
  float* rootfeat        = (float*)ws;          ws += (size_t)NBAG * DIM * 4;
  float* nw              = (float*)ws;          ws += (size_t)NBAG * NPB * 4;
  unsigned* lvlbuf       = (unsigned*)ws;       ws += (size_t)NBAG * NSTEP * 4;
  unsigned* cnt          = (unsigned*)ws;       ws += (size_t)NBAG * 64 * 4;
  unsigned* bagoff       = (unsigned*)ws;       ws += (size_t)64 * 512 * 4;
  unsigned* levtot       = (unsigned*)ws;       ws += 64 * 4;
  unsigned* off          = (unsigned*)ws;       ws += 128 * 4;
  unsigned* wl           = (unsigned*)ws;       ws += (size_t)NBAG * NSTEP * 4;

  k_prep<<<NBAG, 1024, 0, stream>>>(rep, nw, tfeats, w1, w1b, w2, w2b);
  k_merge_levels<<<NBAG / 4, 256, 0, stream>>>(nw, lvlbuf, cnt);
  k_bagscan<<<63, 512, 0, stream>>>(cnt, bagoff, levtot);
  k_scatter<<<126, 256, 0, stream>>>(lvlbuf, levtot, bagoff, wl, off);

  for (int l = 1; l <= LMAX; l++) {
    int cap = 64 / (l + 1); if (cap > 32) cap = 32;
    int capM = 2 * cap;                       // 256-row M-tiles capacity
    k_fc<2 * DIM, true><<<dim3(8 * capM), 512, 0, stream>>>(
        tfeats, w1b, b1, wl, off, hbuf, nullptr, nullptr, l);
    k_fc<DIM, false><<<dim3(8 * capM), 512, 0, stream>>>(
        hbuf, w2b, b2, wl, off, nullptr, tfeats, rootfeat, l);
  }
  k_deep<<<NBAG, 1024, 0, stream>>>(tfeats, w1b, b1, w2b, b2, lvlbuf, rootfeat,
                                    rel, out);
}